// Round 4
// baseline (208.090 us; speedup 1.0000x reference)
//
#include <hip/hip_runtime.h>
#include <math.h>

#define K_CODES 512
#define DIM 64
#define NPTS (32 * 4096)   // 131072 points (B*HW)
#define NQ (NPTS * DIM)    // 8388608 quant_out elements

// d_out layout (floats): [quant_out: 8388608][loss: 1][indices-as-float: 131072]

__global__ void init_kernel(float* __restrict__ loss) { loss[0] = 0.0f; }

// Fused: per-point argmin over codebook + gather/store quant_out + loss accum.
// argmin_k ||x-e_k||^2  ==  argmax_k (x.e_k - 0.5*||e_k||^2)
__global__ __launch_bounds__(256) void vq_kernel(const float* __restrict__ qin,
                                                 const float* __restrict__ cb,
                                                 float* __restrict__ out,
                                                 float* __restrict__ loss_acc,
                                                 float* __restrict__ idx_out) {
    __shared__ float shalf[K_CODES];
    int tid = threadIdx.x;
    for (int kk = 0; kk < K_CODES; kk += 256) {
        int k = kk + tid;
        const float4* c4 = (const float4*)(cb + k * DIM);
        float s0 = 0.f, s1 = 0.f, s2 = 0.f, s3 = 0.f;
#pragma unroll
        for (int i = 0; i < DIM / 4; ++i) {
            float4 c = c4[i];
            s0 = fmaf(c.x, c.x, s0);
            s1 = fmaf(c.y, c.y, s1);
            s2 = fmaf(c.z, c.z, s2);
            s3 = fmaf(c.w, c.w, s3);
        }
        shalf[k] = 0.5f * ((s0 + s1) + (s2 + s3));
    }
    __syncthreads();

    int n = blockIdx.x * 256 + tid; // 0..131071
    int b = n >> 12;
    int hw = n & 4095;
    // qin[b, c, h, w] = qin[b*262144 + c*4096 + hw]
    const float* base = qin + ((size_t)b << 18) + hw;

    float x[DIM];
#pragma unroll
    for (int d = 0; d < DIM; ++d) x[d] = base[(size_t)d << 12];

    float bscore = -INFINITY;
    int bidx = 0;
#pragma unroll 2
    for (int k = 0; k < K_CODES; ++k) {
        const float4* c4 = (const float4*)(cb + k * DIM); // wave-uniform address
        float d0 = 0.f, d1 = 0.f, d2 = 0.f, d3 = 0.f;
#pragma unroll
        for (int i = 0; i < DIM / 4; ++i) {
            float4 c = c4[i];
            d0 = fmaf(x[4 * i + 0], c.x, d0);
            d1 = fmaf(x[4 * i + 1], c.y, d1);
            d2 = fmaf(x[4 * i + 2], c.z, d2);
            d3 = fmaf(x[4 * i + 3], c.w, d3);
        }
        float score = ((d0 + d1) + (d2 + d3)) - shalf[k];
        if (score > bscore) { bscore = score; bidx = k; }
    }
    idx_out[n] = (float)bidx;

    // Gather chosen code, write output (same [b,d,hw] indexing as qin), loss.
    const float* crow = cb + bidx * DIM;
    float* obase = out + ((size_t)b << 18) + hw;
    float l0 = 0.f, l1 = 0.f, l2 = 0.f, l3 = 0.f;
#pragma unroll
    for (int d = 0; d < DIM; d += 4) {
        float v0 = crow[d + 0], v1 = crow[d + 1], v2 = crow[d + 2], v3 = crow[d + 3];
        obase[(size_t)(d + 0) << 12] = v0;
        obase[(size_t)(d + 1) << 12] = v1;
        obase[(size_t)(d + 2) << 12] = v2;
        obase[(size_t)(d + 3) << 12] = v3;
        float e0 = v0 - x[d + 0], e1 = v1 - x[d + 1];
        float e2 = v2 - x[d + 2], e3 = v3 - x[d + 3];
        l0 = fmaf(e0, e0, l0);
        l1 = fmaf(e1, e1, l1);
        l2 = fmaf(e2, e2, l2);
        l3 = fmaf(e3, e3, l3);
    }
    float s = (l0 + l1) + (l2 + l3);

    // wave (64-lane) reduction, then block, then one atomic per block
#pragma unroll
    for (int off = 32; off > 0; off >>= 1) s += __shfl_down(s, off);
    __shared__ float wsum[4];
    int lane = tid & 63, wid = tid >> 6;
    if (lane == 0) wsum[wid] = s;
    __syncthreads();
    if (tid == 0) atomicAdd(loss_acc, (wsum[0] + wsum[1]) + (wsum[2] + wsum[3]));
}

__global__ void finalize_kernel(float* __restrict__ loss) {
    // loss = (1 + BETA) * mean(diff^2), BETA = 0.2
    loss[0] = 1.2f * loss[0] / 8388608.0f;
}

extern "C" void kernel_launch(void* const* d_in, const int* in_sizes, int n_in,
                              void* d_out, int out_size, void* d_ws, size_t ws_size,
                              hipStream_t stream) {
    const float* qin = (const float*)d_in[0]; // (32,64,64,64) f32
    const float* cb = (const float*)d_in[1];  // (512,64) f32
    float* out = (float*)d_out;               // quant_out: 8388608 floats
    float* loss_out = out + NQ;               // 1 float
    float* idx_out = out + NQ + 1;            // 131072 floats (indices as float)

    init_kernel<<<1, 1, 0, stream>>>(loss_out);
    vq_kernel<<<NPTS / 256, 256, 0, stream>>>(qin, cb, out, loss_out, idx_out);
    finalize_kernel<<<1, 1, 0, stream>>>(loss_out);
}

// Round 6
// 164.795 us; speedup vs baseline: 1.2627x; 1.2627x over previous
//
#include <hip/hip_runtime.h>
#include <math.h>

#define K_CODES 512
#define DIM 64
#define NPTS (32 * 4096)   // 131072 points (B*HW)
#define NQ (NPTS * DIM)    // 8388608 quant_out elements
#define KSPLIT 4
#define KRANGE (K_CODES / KSPLIT) // 128 codes per wave
#define PPB 64             // points per block (one per lane)

// d_out layout (floats): [quant_out: 8388608][loss: 1][indices-as-float: 131072]

__global__ void init_kernel(float* __restrict__ loss) { loss[0] = 0.0f; }

// Block: 256 threads = 4 waves. Wave w scans codes [w*128, w*128+128) for the
// block's 64 points (point = lane). Combine in LDS, then gather/store/loss
// with dims partitioned 16-per-wave (compile-time x[] indexing).
__global__ __launch_bounds__(256) void vq_kernel(const float* __restrict__ qin,
                                                 const float* __restrict__ cb,
                                                 float* __restrict__ out,
                                                 float* __restrict__ loss_acc,
                                                 float* __restrict__ idx_out) {
    __shared__ float shalf[K_CODES];
    __shared__ float sscore[KSPLIT][PPB];
    __shared__ int   sidx[KSPLIT][PPB];
    __shared__ int   sfinal[PPB];
    __shared__ float wsum[4];

    int tid = threadIdx.x;
    int lane = tid & 63;
    int w = tid >> 6;

    // cooperative 0.5*||e_k||^2 table (2 rounds of 256 codes)
    for (int kk = 0; kk < K_CODES; kk += 256) {
        int k = kk + tid;
        const float4* c4 = (const float4*)(cb + k * DIM);
        float s0 = 0.f, s1 = 0.f, s2 = 0.f, s3 = 0.f;
#pragma unroll
        for (int i = 0; i < DIM / 4; ++i) {
            float4 c = c4[i];
            s0 = fmaf(c.x, c.x, s0); s1 = fmaf(c.y, c.y, s1);
            s2 = fmaf(c.z, c.z, s2); s3 = fmaf(c.w, c.w, s3);
        }
        shalf[k] = 0.5f * ((s0 + s1) + (s2 + s3));
    }

    int n = blockIdx.x * PPB + lane; // 0..131071
    int b = n >> 12;
    int hw = n & 4095;
    const float* base = qin + ((size_t)b << 18) + hw;

    float x[DIM];
#pragma unroll
    for (int d = 0; d < DIM; ++d) x[d] = base[(size_t)d << 12];

    __syncthreads();

    // scan this wave's K-range; k0 forced to SGPR so codebook loads stay scalar
    int k0 = __builtin_amdgcn_readfirstlane(w * KRANGE);
    float bscore = -INFINITY;
    int bidx = k0;
#pragma unroll 2
    for (int kk = 0; kk < KRANGE; ++kk) {
        int k = k0 + kk;
        const float4* c4 = (const float4*)(cb + (size_t)k * DIM);
        float d0 = 0.f, d1 = 0.f, d2 = 0.f, d3 = 0.f;
#pragma unroll
        for (int i = 0; i < DIM / 4; ++i) {
            float4 c = c4[i];
            d0 = fmaf(x[4 * i + 0], c.x, d0);
            d1 = fmaf(x[4 * i + 1], c.y, d1);
            d2 = fmaf(x[4 * i + 2], c.z, d2);
            d3 = fmaf(x[4 * i + 3], c.w, d3);
        }
        float score = ((d0 + d1) + (d2 + d3)) - shalf[k];
        if (score > bscore) { bscore = score; bidx = k; } // strict: first/smallest k wins ties
    }
    sscore[w][lane] = bscore;
    sidx[w][lane] = bidx;
    __syncthreads();

    // combine 4 ranges (wave 0); strict > keeps lower range => smallest k on ties
    if (w == 0) {
        float s = sscore[0][lane];
        int i = sidx[0][lane];
#pragma unroll
        for (int ww = 1; ww < KSPLIT; ++ww) {
            float s2 = sscore[ww][lane];
            int i2 = sidx[ww][lane];
            if (s2 > s) { s = s2; i = i2; }
        }
        sfinal[lane] = i;
        idx_out[n] = (float)i;
    }
    __syncthreads();

    // gather + store + loss: wave w handles dims [w*16, w*16+16) for point=lane.
    // Compile-time x[] indexing per branch (avoid runtime-indexed VGPR array).
    int ci = sfinal[lane];
    float lsum;
#define GATHER_BODY(W)                                                          \
    {                                                                           \
        const float* crow = cb + ci * DIM + (W)*16;                             \
        float* obase = out + ((size_t)b << 18) + ((size_t)((W)*16) << 12) + hw; \
        float l0 = 0.f, l1 = 0.f, l2 = 0.f, l3 = 0.f;                           \
        _Pragma("unroll") for (int j = 0; j < 16; j += 4) {                     \
            float v0 = crow[j + 0], v1 = crow[j + 1];                           \
            float v2 = crow[j + 2], v3 = crow[j + 3];                           \
            obase[(size_t)(j + 0) << 12] = v0;                                  \
            obase[(size_t)(j + 1) << 12] = v1;                                  \
            obase[(size_t)(j + 2) << 12] = v2;                                  \
            obase[(size_t)(j + 3) << 12] = v3;                                  \
            float e0 = v0 - x[(W)*16 + j + 0], e1 = v1 - x[(W)*16 + j + 1];     \
            float e2 = v2 - x[(W)*16 + j + 2], e3 = v3 - x[(W)*16 + j + 3];     \
            l0 = fmaf(e0, e0, l0); l1 = fmaf(e1, e1, l1);                       \
            l2 = fmaf(e2, e2, l2); l3 = fmaf(e3, e3, l3);                       \
        }                                                                       \
        lsum = (l0 + l1) + (l2 + l3);                                           \
    }
    if (w == 0) GATHER_BODY(0)
    else if (w == 1) GATHER_BODY(1)
    else if (w == 2) GATHER_BODY(2)
    else GATHER_BODY(3)
#undef GATHER_BODY

    // wave reduce then one atomic per block
    float s = lsum;
#pragma unroll
    for (int off = 32; off > 0; off >>= 1) s += __shfl_down(s, off);
    if (lane == 0) wsum[w] = s;
    __syncthreads();
    if (tid == 0) atomicAdd(loss_acc, (wsum[0] + wsum[1]) + (wsum[2] + wsum[3]));
}

__global__ void finalize_kernel(float* __restrict__ loss) {
    // loss = (1 + BETA) * mean(diff^2), BETA = 0.2
    loss[0] = 1.2f * loss[0] / 8388608.0f;
}

extern "C" void kernel_launch(void* const* d_in, const int* in_sizes, int n_in,
                              void* d_out, int out_size, void* d_ws, size_t ws_size,
                              hipStream_t stream) {
    const float* qin = (const float*)d_in[0]; // (32,64,64,64) f32
    const float* cb = (const float*)d_in[1];  // (512,64) f32
    float* out = (float*)d_out;               // quant_out: 8388608 floats
    float* loss_out = out + NQ;               // 1 float
    float* idx_out = out + NQ + 1;            // 131072 floats (indices as float)

    init_kernel<<<1, 1, 0, stream>>>(loss_out);
    vq_kernel<<<NPTS / PPB, 256, 0, stream>>>(qin, cb, out, loss_out, idx_out);
    finalize_kernel<<<1, 1, 0, stream>>>(loss_out);
}